// Round 13
// baseline (240.074 us; speedup 1.0000x reference)
//
#include <hip/hip_runtime.h>
#include <hip/hip_bf16.h>

#define N 4096
#define IN_DIM 256
#define HID 64
#define NHEADS 4
#define OUT_DIM 128
#define LOG2E 1.44269504088896340736f

typedef __attribute__((ext_vector_type(8))) short bf16x8;
typedef __attribute__((ext_vector_type(4))) float f32x4;

// Two-term bf16 split: v ~= hi + lo with |err| ~ 2^-17 |v|.
__device__ __forceinline__ ushort2 bsplit(float v) {
    const ushort h = __hip_bfloat16_raw(__float2bfloat16(v)).x;
    const float vh = __uint_as_float((unsigned)h << 16);
    const ushort l = __hip_bfloat16_raw(__float2bfloat16(v - vh)).x;
    return make_ushort2(h, l);
}

// ---------------------------------------------------------------------------
// prep_kernel = gemm1-MFMA (blocks 0..255) + mask pack (blocks 256..1279).
// Row table C1 = e^(-f1/2); attention P-gen is P' = max(E2[j], C1_i*S2[j])
// (E1 cancels in the softmax ratio -- verified R11). UNCHANGED from R12.
// ---------------------------------------------------------------------------
__global__ __launch_bounds__(256, 4) void prep_kernel(
        const float* __restrict__ x, const float* __restrict__ W,
        const float* __restrict__ a, const int* __restrict__ adj,
        __hip_bfloat16* __restrict__ WhB,
        float* __restrict__ C1, float* __restrict__ E2, float* __restrict__ S2,
        unsigned* __restrict__ maskT) {
    const int t = threadIdx.x;
    if (blockIdx.x < 256) {
        const int h = t >> 6, lane = t & 63, m = lane & 15, quad = lane >> 4;
        const int i0 = blockIdx.x * 16;
        const float* xrow = x + (size_t)(i0 + m) * IN_DIM;
        const float* Wp = W + (size_t)h * IN_DIM * HID;
        const f32x4 zero = {0.f, 0.f, 0.f, 0.f};
        f32x4 acc[4] = {zero, zero, zero, zero};
        for (int ks = 0; ks < 8; ks++) {
            const int kb = ks * 32 + quad * 8;
            const float4 xa = *(const float4*)(xrow + kb);
            const float4 xb = *(const float4*)(xrow + kb + 4);
            const float xf[8] = {xa.x, xa.y, xa.z, xa.w, xb.x, xb.y, xb.z, xb.w};
            bf16x8 xh, xl;
#pragma unroll
            for (int e = 0; e < 8; e++) {
                const ushort2 s = bsplit(xf[e]);
                xh[e] = (short)s.x; xl[e] = (short)s.y;
            }
#pragma unroll
            for (int ct = 0; ct < 4; ct++) {
                bf16x8 wh, wl;
#pragma unroll
                for (int e = 0; e < 8; e++) {
                    const ushort2 s =
                        bsplit(Wp[(size_t)(kb + e) * HID + ct * 16 + m]);
                    wh[e] = (short)s.x; wl[e] = (short)s.y;
                }
                acc[ct] = __builtin_amdgcn_mfma_f32_16x16x32_bf16(
                    xh, wh, acc[ct], 0, 0, 0);
                acc[ct] = __builtin_amdgcn_mfma_f32_16x16x32_bf16(
                    xl, wh, acc[ct], 0, 0, 0);
                acc[ct] = __builtin_amdgcn_mfma_f32_16x16x32_bf16(
                    xh, wl, acc[ct], 0, 0, 0);
            }
        }
        const int jblk = i0 >> 5, jb2 = (i0 >> 4) & 1;
#pragma unroll
        for (int ct = 0; ct < 4; ct++) {
#pragma unroll
            for (int r = 0; r < 4; r++) {
                const int jo = quad * 4 + r;
                const int lane_idx = m + 16 * (2 * jb2 + (jo >> 3));
                WhB[((((size_t)h * (N / 32) + jblk) * 4 + ct) * 64 + lane_idx) *
                        8 + (jo & 7)] = __float2bfloat16(acc[ct][r]);
            }
        }
        float av1[4], av2[4];
#pragma unroll
        for (int ct = 0; ct < 4; ct++) {
            av1[ct] = a[h * 2 * HID + ct * 16 + m];
            av2[ct] = a[h * 2 * HID + HID + ct * 16 + m];
        }
        float s1[4], s2[4];
#pragma unroll
        for (int r = 0; r < 4; r++) {
            s1[r] = 0.f; s2[r] = 0.f;
#pragma unroll
            for (int ct = 0; ct < 4; ct++) {
                s1[r] += acc[ct][r] * av1[ct];
                s2[r] += acc[ct][r] * av2[ct];
            }
        }
#pragma unroll
        for (int mm = 8; mm > 0; mm >>= 1) {
#pragma unroll
            for (int r = 0; r < 4; r++) {
                s1[r] += __shfl_xor(s1[r], mm, 64);
                s2[r] += __shfl_xor(s2[r], mm, 64);
            }
        }
        if (m == 0) {
#pragma unroll
            for (int r = 0; r < 4; r++) {
                const size_t ix = (size_t)h * N + i0 + quad * 4 + r;
                C1[ix] = __builtin_amdgcn_exp2f(s1[r] * (-0.5f * LOG2E));
                E2[ix] = __builtin_amdgcn_exp2f(s2[r] * LOG2E);
                S2[ix] = __builtin_amdgcn_exp2f(s2[r] * (0.5f * LOG2E));
            }
        }
    } else {
        const int lane = t & 63, w = t >> 6;
        const int i = (blockIdx.x - 256) * 4 + w;      // one row per wave
        const int4* arow = (const int4*)(adj + (size_t)i * N);
        for (int jb = 0; jb < N / 256; jb++) {
            const int4 a4 = arow[jb * 64 + lane];
            unsigned long long bal[4];
            bal[0] = __ballot(a4.x > 0);
            bal[1] = __ballot(a4.y > 0);
            bal[2] = __ballot(a4.z > 0);
            bal[3] = __ballot(a4.w > 0);
            if (lane < 8) {
                unsigned word = 0;
#pragma unroll
                for (int e = 0; e < 4; e++) {
                    unsigned xv = (unsigned)(bal[e] >> (8 * lane)) & 0xFFu;
                    xv = (xv | (xv << 12)) & 0x000F000Fu;
                    xv = (xv | (xv << 6))  & 0x03030303u;
                    xv = (xv | (xv << 3))  & 0x11111111u;
                    word |= xv << e;
                }
                maskT[(size_t)(jb * 8 + lane) * N + i] = word;
            }
        }
    }
}

// ---------------------------------------------------------------------------
// R13: attn1+gemm2 fused, NO grid sync needed. Block = 16 rows x ALL 4 heads
// -> block owns all 256 h1 channels for its rows; h1 passes through LDS and
// gemm2 runs in-block after __syncthreads(). Deletes one dispatch boundary,
// gemm2's launch, and the 8MB h1 global round-trip. Total attn MFMA/P-gen
// work unchanged (same rowxhead area); mask loads dedup 4x; B-frag traffic
// 2x (L2-resident, measured harmless R1).
// Grid 256 blocks x 512 thr (8 waves = G=8 j-groups, KSTEPS=16).
// All pipeline state in NAMED per-head variables (rule-#20-safe).
// ---------------------------------------------------------------------------
__global__ __launch_bounds__(512, 2) void attn1_gemm2(
        const unsigned* __restrict__ maskT,              // [N/32][N]
        const __hip_bfloat16* __restrict__ WhB1,         // [4][N/32][4][64][8]
        const float* __restrict__ C1a, const float* __restrict__ E2a,
        const float* __restrict__ S2a,
        const float* __restrict__ W2, const float* __restrict__ a2,
        __hip_bfloat16* __restrict__ WhB2,
        float* __restrict__ C1b, float* __restrict__ E2b,
        float* __restrict__ S2b) {
    constexpr int G = 8;
    constexpr int KSTEPS = N / (32 * G);       // 16
    __shared__ float sh[8704];                 // [g*16+row][4ct*17]
    __shared__ float dsh[128];                 // [g*16+row] per-head row sums
    __shared__ float h1s[16 * 260];            // 16 rows x 256 ch (+4 pad)
    __shared__ float fred[8 * 16 * 2];
    const int t = threadIdx.x;
    const int g = t >> 6, lane = t & 63;
    const int m = lane & 15, quad = lane >> 4;
    const int i0 = blockIdx.x * 16;

    // ---------------- attn phase (4 heads, 16 rows) ----------------
    const float c1v0 = C1a[0 * N + i0 + m];
    const float c1v1 = C1a[1 * N + i0 + m];
    const float c1v2 = C1a[2 * N + i0 + m];
    const float c1v3 = C1a[3 * N + i0 + m];

    const unsigned* mp = maskT + (size_t)(g * KSTEPS) * N + i0 + m;
    const int tb = g * (N / G) + quad * 8;
    const float* ep0 = E2a + 0 * N + tb; const float* sp0 = S2a + 0 * N + tb;
    const float* ep1 = E2a + 1 * N + tb; const float* sp1 = S2a + 1 * N + tb;
    const float* ep2 = E2a + 2 * N + tb; const float* sp2 = S2a + 2 * N + tb;
    const float* ep3 = E2a + 3 * N + tb; const float* sp3 = S2a + 3 * N + tb;
    const bf16x8* bbase = (const bf16x8*)WhB1 + (size_t)(g * KSTEPS) * 4 * 64 + lane;
    const bf16x8* bp0 = bbase + (size_t)0 * (N / 32) * 4 * 64;
    const bf16x8* bp1 = bbase + (size_t)1 * (N / 32) * 4 * 64;
    const bf16x8* bp2 = bbase + (size_t)2 * (N / 32) * 4 * 64;
    const bf16x8* bp3 = bbase + (size_t)3 * (N / 32) * 4 * 64;

    const f32x4 zero = {0.f, 0.f, 0.f, 0.f};
    f32x4 acc0[4] = {zero, zero, zero, zero};
    f32x4 acc1[4] = {zero, zero, zero, zero};
    f32x4 acc2[4] = {zero, zero, zero, zero};
    f32x4 acc3[4] = {zero, zero, zero, zero};
    f32x4 sac0 = zero, sac1 = zero, sac2 = zero, sac3 = zero;
    const short one_bf = (short)0x3F80;
    const bf16x8 ones = {one_bf, one_bf, one_bf, one_bf,
                         one_bf, one_bf, one_bf, one_bf};

    for (int ks = 0; ks < KSTEPS; ks++) {
        const unsigned mwrd = *mp; mp += N;
        const unsigned mword = (mwrd >> (quad * 8)) & 0xFFu;
        const unsigned spread = mword * 0x8001u;

        auto headstep = [&](float c1, const float*& ep_, const float*& sp_,
                            const bf16x8*& bp_, f32x4 (&acc_)[4], f32x4& sac_) {
            const float4 e2lo = *(const float4*)(ep_);
            const float4 e2hi = *(const float4*)(ep_ + 4);
            const float4 s2lo = *(const float4*)(sp_);
            const float4 s2hi = *(const float4*)(sp_ + 4);
            ep_ += 32; sp_ += 32;
            bf16x8 bf0 = bp_[0 * 64], bf1 = bp_[1 * 64];
            bf16x8 bf2 = bp_[2 * 64], bf3 = bp_[3 * 64];
            bp_ += 4 * 64;
            const float Ee[8] = {e2lo.x, e2lo.y, e2lo.z, e2lo.w,
                                 e2hi.x, e2hi.y, e2hi.z, e2hi.w};
            const float Se[8] = {s2lo.x, s2lo.y, s2lo.z, s2lo.w,
                                 s2hi.x, s2hi.y, s2hi.z, s2hi.w};
            float p[8];
#pragma unroll
            for (int e = 0; e < 8; e++)
                p[e] = fmaxf(Ee[e], c1 * Se[e]);
            union { bf16x8 v; unsigned u32[4]; __hip_bfloat162 h2[4]; } u;
#pragma unroll
            for (int e2 = 0; e2 < 4; e2++) {
                u.h2[e2] = __float22bfloat162_rn(
                    make_float2(p[2 * e2], p[2 * e2 + 1]));
                const unsigned mk =
                    ((spread >> (2 * e2)) & 0x00010001u) * 0xFFFFu;
                u.u32[e2] &= mk;
            }
            const bf16x8 afr = u.v;
            acc_[0] = __builtin_amdgcn_mfma_f32_16x16x32_bf16(afr, bf0, acc_[0], 0, 0, 0);
            acc_[1] = __builtin_amdgcn_mfma_f32_16x16x32_bf16(afr, bf1, acc_[1], 0, 0, 0);
            acc_[2] = __builtin_amdgcn_mfma_f32_16x16x32_bf16(afr, bf2, acc_[2], 0, 0, 0);
            acc_[3] = __builtin_amdgcn_mfma_f32_16x16x32_bf16(afr, bf3, acc_[3], 0, 0, 0);
            sac_ = __builtin_amdgcn_mfma_f32_16x16x32_bf16(afr, ones, sac_, 0, 0, 0);
        };
        headstep(c1v0, ep0, sp0, bp0, acc0, sac0);
        headstep(c1v1, ep1, sp1, bp1, acc1, sac1);
        headstep(c1v2, ep2, sp2, bp2, acc2, sac2);
        headstep(c1v3, ep3, sp3, bp3, acc3, sac3);
    }

    // ---- per-head epilogue rounds: reduce over G into LDS h1s ----
    auto epi = [&](f32x4 (&acc_)[4], f32x4& sac_, int hh) {
#pragma unroll
        for (int ct = 0; ct < 4; ct++)
#pragma unroll
            for (int r = 0; r < 4; r++)
                sh[(g * 16 + quad * 4 + r) * 68 + ct * 17 + m] = acc_[ct][r];
        if (m == 0) {
#pragma unroll
            for (int r = 0; r < 4; r++)
                dsh[g * 16 + quad * 4 + r] = sac_[r];
        }
        __syncthreads();
        if (t < 256) {
            const int row = t >> 4, col = t & 15;
            float ss = 0.f;
#pragma unroll
            for (int gg = 0; gg < G; gg++) ss += dsh[gg * 16 + row];
#pragma unroll
            for (int ct = 0; ct < 4; ct++) {
                float av = 0.f;
#pragma unroll
                for (int gg = 0; gg < G; gg++)
                    av += sh[(gg * 16 + row) * 68 + ct * 17 + col];
                float v = av / ss;
                v = (v > 0.f) ? v : (__builtin_amdgcn_exp2f(v * LOG2E) - 1.f);
                h1s[row * 260 + hh * 64 + ct * 16 + col] = v;
            }
        }
        __syncthreads();
    };
    epi(acc0, sac0, 0);
    epi(acc1, sac1, 1);
    epi(acc2, sac2, 2);
    epi(acc3, sac3, 3);

    // ---------------- gemm2 phase (in-block, h1 from LDS) ----------------
    {
        const float* wp = W2 + g * 16 + m;
        f32x4 gacc = zero;
        for (int ks2 = 0; ks2 < 8; ks2++) {
            const int kb = ks2 * 32 + quad * 8;
            float xf[8];
#pragma unroll
            for (int e = 0; e < 8; e++) xf[e] = h1s[m * 260 + kb + e];
            bf16x8 xh, xl, wh, wl;
#pragma unroll
            for (int e = 0; e < 8; e++) {
                const ushort2 s = bsplit(xf[e]);
                xh[e] = (short)s.x; xl[e] = (short)s.y;
            }
#pragma unroll
            for (int e = 0; e < 8; e++) {
                const ushort2 s = bsplit(wp[(size_t)(kb + e) * OUT_DIM]);
                wh[e] = (short)s.x; wl[e] = (short)s.y;
            }
            gacc = __builtin_amdgcn_mfma_f32_16x16x32_bf16(xh, wh, gacc, 0, 0, 0);
            gacc = __builtin_amdgcn_mfma_f32_16x16x32_bf16(xl, wh, gacc, 0, 0, 0);
            gacc = __builtin_amdgcn_mfma_f32_16x16x32_bf16(xh, wl, gacc, 0, 0, 0);
        }
        // ---- WhB2 frag store: j = i0+quad*4+r, c = g*16+m ----
        const int jblk = i0 >> 5, jb2 = (i0 >> 4) & 1;
#pragma unroll
        for (int r = 0; r < 4; r++) {
            const int jo = quad * 4 + r;
            const int lane_idx = m + 16 * (2 * jb2 + (jo >> 3));
            WhB2[(((size_t)jblk * 8 + g) * 64 + lane_idx) * 8 + (jo & 7)] =
                __float2bfloat16(gacc[r]);
        }
        // ---- f-reductions -> C1b/E2b/S2b ----
        const float av1 = a2[g * 16 + m], av2 = a2[OUT_DIM + g * 16 + m];
        float s1[4], s2[4];
#pragma unroll
        for (int r = 0; r < 4; r++) { s1[r] = gacc[r] * av1; s2[r] = gacc[r] * av2; }
#pragma unroll
        for (int mm = 8; mm > 0; mm >>= 1) {
#pragma unroll
            for (int r = 0; r < 4; r++) {
                s1[r] += __shfl_xor(s1[r], mm, 64);
                s2[r] += __shfl_xor(s2[r], mm, 64);
            }
        }
        if (m == 0) {
#pragma unroll
            for (int r = 0; r < 4; r++) {
                fred[(g * 16 + quad * 4 + r) * 2 + 0] = s1[r];
                fred[(g * 16 + quad * 4 + r) * 2 + 1] = s2[r];
            }
        }
        __syncthreads();
        if (t < 32) {
            const int row = t & 15, fn = t >> 4;
            float s = 0.f;
#pragma unroll
            for (int w8 = 0; w8 < 8; w8++) s += fred[(w8 * 16 + row) * 2 + fn];
            if (fn) {
                E2b[i0 + row] = __builtin_amdgcn_exp2f(s * LOG2E);
                S2b[i0 + row] = __builtin_amdgcn_exp2f(s * (0.5f * LOG2E));
            } else {
                C1b[i0 + row] = __builtin_amdgcn_exp2f(s * (-0.5f * LOG2E));
            }
        }
    }
}

// ---------------------------------------------------------------------------
// Fused attention layer (layer 2 only now). UNCHANGED from R12 (passed).
// ---------------------------------------------------------------------------
template <int HEADS, int D, int DSL, int G, int MW, int OCC>
__global__ __launch_bounds__(G * 64, OCC) void attn_fused(
        const unsigned* __restrict__ maskT,             // [N/32][N]
        const __hip_bfloat16* __restrict__ WhB,          // [H][N/32][D/16][64][8]
        const float* __restrict__ C1g, const float* __restrict__ E2g,
        const float* __restrict__ S2g,
        float* __restrict__ outp) {
    constexpr int CTtot = D / 16;
    constexpr int CTT = CTtot / DSL;
    constexpr int CC = (D == 64) ? 1 : 2;
    constexpr int KSTEPS = N / (32 * G);
    static_assert(KSTEPS % 2 == 0, "two-step pipeline needs even KSTEPS");
    __shared__ float sh[MW * G * 16 * CC * 17];
    __shared__ float dsh[MW * G * 16];
    const int t = threadIdx.x;
    const int g = t >> 6, lane = t & 63;
    const int m = lane & 15, quad = lane >> 4;
    const int h = blockIdx.y / DSL, slc = blockIdx.y % DSL;
    const int i0 = blockIdx.x * (16 * MW);

    float c1v[MW];
#pragma unroll
    for (int mw = 0; mw < MW; mw++)
        c1v[mw] = C1g[(size_t)h * N + i0 + mw * 16 + m];

    const unsigned* mp = maskT + (size_t)(g * KSTEPS) * N + i0 + m;
    const float* ep = E2g + (size_t)h * N + g * (N / G) + quad * 8;
    const float* sp = S2g + (size_t)h * N + g * (N / G) + quad * 8;
    const bf16x8* bp = (const bf16x8*)WhB +
                       ((size_t)h * (N / 32) * CTtot +
                        (size_t)(g * KSTEPS) * CTtot + slc * CTT) * 64 + lane;

    const f32x4 zero = {0.f, 0.f, 0.f, 0.f};
    f32x4 acc[MW][CTT];
    f32x4 sac[MW];
#pragma unroll
    for (int mw = 0; mw < MW; mw++) {
        sac[mw] = zero;
#pragma unroll
        for (int ct = 0; ct < CTT; ct++) acc[mw][ct] = zero;
    }
    const short one_bf = (short)0x3F80;
    const bf16x8 ones = {one_bf, one_bf, one_bf, one_bf,
                         one_bf, one_bf, one_bf, one_bf};

    unsigned mwrdA[MW], mwrdB[MW];
    float4 e2loA, e2hiA, s2loA, s2hiA;
    float4 e2loB, e2hiB, s2loB, s2hiB;
    bf16x8 bfragA[CTT], bfragB[CTT];

    auto stage = [&](auto& mwrd_, float4& e2lo_, float4& e2hi_,
                     float4& s2lo_, float4& s2hi_, auto& bfrag_) {
#pragma unroll
        for (int mw = 0; mw < MW; mw++) mwrd_[mw] = mp[mw * 16];
        e2lo_ = *(const float4*)(ep);
        e2hi_ = *(const float4*)(ep + 4);
        s2lo_ = *(const float4*)(sp);
        s2hi_ = *(const float4*)(sp + 4);
#pragma unroll
        for (int ct = 0; ct < CTT; ct++) bfrag_[ct] = bp[ct * 64];
        mp += N; ep += 32; sp += 32; bp += CTtot * 64;
    };

    auto compute = [&](const auto& mwrd_, const float4& e2lo_,
                       const float4& e2hi_, const float4& s2lo_,
                       const float4& s2hi_, const auto& bfrag_) {
        const float Ee[8] = {e2lo_.x, e2lo_.y, e2lo_.z, e2lo_.w,
                             e2hi_.x, e2hi_.y, e2hi_.z, e2hi_.w};
        const float Se[8] = {s2lo_.x, s2lo_.y, s2lo_.z, s2lo_.w,
                             s2hi_.x, s2hi_.y, s2hi_.z, s2hi_.w};
        bf16x8 afr[MW];
#pragma unroll
        for (int mw = 0; mw < MW; mw++) {
            const unsigned mword = (mwrd_[mw] >> (quad * 8)) & 0xFFu;
            const unsigned spread = mword * 0x8001u;
            float p[8];
#pragma unroll
            for (int e = 0; e < 8; e++)
                p[e] = fmaxf(Ee[e], c1v[mw] * Se[e]);
            union { bf16x8 v; unsigned u32[4]; __hip_bfloat162 h2[4]; } u;
#pragma unroll
            for (int e2 = 0; e2 < 4; e2++) {
                u.h2[e2] = __float22bfloat162_rn(
                    make_float2(p[2 * e2], p[2 * e2 + 1]));
                const unsigned mk =
                    ((spread >> (2 * e2)) & 0x00010001u) * 0xFFFFu;
                u.u32[e2] &= mk;
            }
            afr[mw] = u.v;
        }
#pragma unroll
        for (int ct = 0; ct < CTT; ct++)
#pragma unroll
            for (int mw = 0; mw < MW; mw++)
                acc[mw][ct] = __builtin_amdgcn_mfma_f32_16x16x32_bf16(
                    afr[mw], bfrag_[ct], acc[mw][ct], 0, 0, 0);
#pragma unroll
        for (int mw = 0; mw < MW; mw++)
            sac[mw] = __builtin_amdgcn_mfma_f32_16x16x32_bf16(
                afr[mw], ones, sac[mw], 0, 0, 0);
    };

    stage(mwrdA, e2loA, e2hiA, s2loA, s2hiA, bfragA);
    for (int ks = 0; ks < KSTEPS; ks += 2) {
        stage(mwrdB, e2loB, e2hiB, s2loB, s2hiB, bfragB);
        compute(mwrdA, e2loA, e2hiA, s2loA, s2hiA, bfragA);
        if (ks + 2 < KSTEPS)
            stage(mwrdA, e2loA, e2hiA, s2loA, s2hiA, bfragA);
        compute(mwrdB, e2loB, e2hiB, s2loB, s2hiB, bfragB);
    }

#pragma unroll
    for (int rd = 0; rd < CTT / CC; rd++) {
#pragma unroll
        for (int mw = 0; mw < MW; mw++) {
#pragma unroll
            for (int cc = 0; cc < CC; cc++) {
#pragma unroll
                for (int r = 0; r < 4; r++)
                    sh[(((mw * G + g) * 16 + quad * 4 + r) * CC + cc) * 17 + m] =
                        acc[mw][rd * CC + cc][r];
            }
            if (rd == 0 && m == 0) {
#pragma unroll
                for (int r = 0; r < 4; r++)
                    dsh[(mw * G + g) * 16 + quad * 4 + r] = sac[mw][r];
            }
        }
        __syncthreads();
        if (t < 16 * CC * 16) {
            int row, chl;
            if (D == 64) { row = t & 15; chl = (t >> 4) & 15; }
            else         { chl = t & 31; row = (t >> 5) & 15; }
#pragma unroll
            for (int mw = 0; mw < MW; mw++) {
                float av = 0.f, ss = 0.f;
#pragma unroll
                for (int gg = 0; gg < G; gg++) {
                    av += sh[(((mw * G + gg) * 16 + row) * CC + (chl >> 4)) * 17 +
                             (chl & 15)];
                    ss += dsh[(mw * G + gg) * 16 + row];
                }
                float v = av / ss;
                v = (v > 0.f) ? v : (__builtin_amdgcn_exp2f(v * LOG2E) - 1.f);
                const int chg = h * D + slc * (CTT * 16) + rd * CC * 16 + chl;
                const int irow = i0 + mw * 16 + row;
                if (D == 64)
                    outp[(size_t)irow * (NHEADS * HID) + chg] = v;
                else
                    outp[(size_t)irow * D + chg] = v;
            }
        }
        __syncthreads();
    }
}

// ---------------------------------------------------------------------------
extern "C" void kernel_launch(void* const* d_in, const int* in_sizes, int n_in,
                              void* d_out, int out_size, void* d_ws, size_t ws_size,
                              hipStream_t stream) {
    const float* x   = (const float*)d_in[0];
    const int*   adj = (const int*)d_in[1];
    const float* Wh_ = (const float*)d_in[2];
    const float* ah  = (const float*)d_in[3];
    const float* W2  = (const float*)d_in[4];
    const float* a2  = (const float*)d_in[5];
    float* out = (float*)d_out;

    float* ws = (float*)d_ws;
    float* C1a = ws;                                    // 4*N each
    float* E2a = C1a + (size_t)NHEADS * N;
    float* S2a = E2a + (size_t)NHEADS * N;
    float* C1b = S2a + (size_t)NHEADS * N;              // N each
    float* E2b = C1b + N;
    float* S2b = E2b + N;
    float* h1  = S2b + N;                               // (unused after R13)
    __hip_bfloat16* WhB1 = (__hip_bfloat16*)(h1 + (size_t)IN_DIM * N);  // 2MB
    __hip_bfloat16* WhB2 = WhB1 + (size_t)NHEADS * HID * N;            // 1MB
    unsigned* maskT = (unsigned*)(WhB2 + (size_t)OUT_DIM * N);         // 2MB

    prep_kernel<<<1280, 256, 0, stream>>>(x, Wh_, ah, adj, WhB1,
                                          C1a, E2a, S2a, maskT);
    attn1_gemm2<<<N / 16, 512, 0, stream>>>(maskT, WhB1, C1a, E2a, S2a,
                                            W2, a2, WhB2, C1b, E2b, S2b);
    attn_fused<1, OUT_DIM, 1, 8, 1, 2>
        <<<dim3(N / 16, 1), 512, 0, stream>>>(maskT, WhB2,
                                              C1b, E2b, S2b, out);
}

// Round 14
// 166.641 us; speedup vs baseline: 1.4407x; 1.4407x over previous
//
#include <hip/hip_runtime.h>
#include <hip/hip_bf16.h>

#define N 4096
#define IN_DIM 256
#define HID 64
#define NHEADS 4
#define OUT_DIM 128
#define LOG2E 1.44269504088896340736f

typedef __attribute__((ext_vector_type(8))) short bf16x8;
typedef __attribute__((ext_vector_type(4))) float f32x4;

// Two-term bf16 split: v ~= hi + lo with |err| ~ 2^-17 |v|.
__device__ __forceinline__ ushort2 bsplit(float v) {
    const ushort h = __hip_bfloat16_raw(__float2bfloat16(v)).x;
    const float vh = __uint_as_float((unsigned)h << 16);
    const ushort l = __hip_bfloat16_raw(__float2bfloat16(v - vh)).x;
    return make_ushort2(h, l);
}

// ---------------------------------------------------------------------------
// prep_kernel = gemm1-MFMA (blocks 0..255) + mask pack (blocks 256..1279).
// Row table C1 = e^(-f1/2); attention P-gen is P' = max(E2[j], C1_i*S2[j])
// (E1 cancels in the softmax ratio -- verified R11).
// ---------------------------------------------------------------------------
__global__ __launch_bounds__(256, 4) void prep_kernel(
        const float* __restrict__ x, const float* __restrict__ W,
        const float* __restrict__ a, const int* __restrict__ adj,
        __hip_bfloat16* __restrict__ WhB,
        float* __restrict__ C1, float* __restrict__ E2, float* __restrict__ S2,
        unsigned* __restrict__ maskT) {
    const int t = threadIdx.x;
    if (blockIdx.x < 256) {
        // ---------------- gemm1 via MFMA ----------------
        const int h = t >> 6, lane = t & 63, m = lane & 15, quad = lane >> 4;
        const int i0 = blockIdx.x * 16;
        const float* xrow = x + (size_t)(i0 + m) * IN_DIM;
        const float* Wp = W + (size_t)h * IN_DIM * HID;
        const f32x4 zero = {0.f, 0.f, 0.f, 0.f};
        f32x4 acc[4] = {zero, zero, zero, zero};
        for (int ks = 0; ks < 8; ks++) {
            const int kb = ks * 32 + quad * 8;
            const float4 xa = *(const float4*)(xrow + kb);
            const float4 xb = *(const float4*)(xrow + kb + 4);
            const float xf[8] = {xa.x, xa.y, xa.z, xa.w, xb.x, xb.y, xb.z, xb.w};
            bf16x8 xh, xl;
#pragma unroll
            for (int e = 0; e < 8; e++) {
                const ushort2 s = bsplit(xf[e]);
                xh[e] = (short)s.x; xl[e] = (short)s.y;
            }
#pragma unroll
            for (int ct = 0; ct < 4; ct++) {
                bf16x8 wh, wl;
#pragma unroll
                for (int e = 0; e < 8; e++) {
                    const ushort2 s =
                        bsplit(Wp[(size_t)(kb + e) * HID + ct * 16 + m]);
                    wh[e] = (short)s.x; wl[e] = (short)s.y;
                }
                acc[ct] = __builtin_amdgcn_mfma_f32_16x16x32_bf16(
                    xh, wh, acc[ct], 0, 0, 0);
                acc[ct] = __builtin_amdgcn_mfma_f32_16x16x32_bf16(
                    xl, wh, acc[ct], 0, 0, 0);
                acc[ct] = __builtin_amdgcn_mfma_f32_16x16x32_bf16(
                    xh, wl, acc[ct], 0, 0, 0);
            }
        }
        // ---- WhB1 frag store: j = i0+quad*4+r, c = ct*16+m ----
        const int jblk = i0 >> 5, jb2 = (i0 >> 4) & 1;
#pragma unroll
        for (int ct = 0; ct < 4; ct++) {
#pragma unroll
            for (int r = 0; r < 4; r++) {
                const int jo = quad * 4 + r;
                const int lane_idx = m + 16 * (2 * jb2 + (jo >> 3));
                WhB[((((size_t)h * (N / 32) + jblk) * 4 + ct) * 64 + lane_idx) *
                        8 + (jo & 7)] = __float2bfloat16(acc[ct][r]);
            }
        }
        // ---- f1/f2 -> C1 / E2,S2 tables ----
        float av1[4], av2[4];
#pragma unroll
        for (int ct = 0; ct < 4; ct++) {
            av1[ct] = a[h * 2 * HID + ct * 16 + m];
            av2[ct] = a[h * 2 * HID + HID + ct * 16 + m];
        }
        float s1[4], s2[4];
#pragma unroll
        for (int r = 0; r < 4; r++) {
            s1[r] = 0.f; s2[r] = 0.f;
#pragma unroll
            for (int ct = 0; ct < 4; ct++) {
                s1[r] += acc[ct][r] * av1[ct];
                s2[r] += acc[ct][r] * av2[ct];
            }
        }
#pragma unroll
        for (int mm = 8; mm > 0; mm >>= 1) {
#pragma unroll
            for (int r = 0; r < 4; r++) {
                s1[r] += __shfl_xor(s1[r], mm, 64);
                s2[r] += __shfl_xor(s2[r], mm, 64);
            }
        }
        if (m == 0) {
#pragma unroll
            for (int r = 0; r < 4; r++) {
                const size_t ix = (size_t)h * N + i0 + quad * 4 + r;
                C1[ix] = __builtin_amdgcn_exp2f(s1[r] * (-0.5f * LOG2E));
                E2[ix] = __builtin_amdgcn_exp2f(s2[r] * LOG2E);
                S2[ix] = __builtin_amdgcn_exp2f(s2[r] * (0.5f * LOG2E));
            }
        }
    } else {
        // ---------------- mask pack (bit-spread, verified R6) ----------------
        const int lane = t & 63, w = t >> 6;
        const int i = (blockIdx.x - 256) * 4 + w;      // one row per wave
        const int4* arow = (const int4*)(adj + (size_t)i * N);
        for (int jb = 0; jb < N / 256; jb++) {
            const int4 a4 = arow[jb * 64 + lane];
            unsigned long long bal[4];
            bal[0] = __ballot(a4.x > 0);
            bal[1] = __ballot(a4.y > 0);
            bal[2] = __ballot(a4.z > 0);
            bal[3] = __ballot(a4.w > 0);
            if (lane < 8) {
                unsigned word = 0;
#pragma unroll
                for (int e = 0; e < 4; e++) {
                    unsigned xv = (unsigned)(bal[e] >> (8 * lane)) & 0xFFu;
                    xv = (xv | (xv << 12)) & 0x000F000Fu;
                    xv = (xv | (xv << 6))  & 0x03030303u;
                    xv = (xv | (xv << 3))  & 0x11111111u;
                    word |= xv << e;
                }
                maskT[(size_t)(jb * 8 + lane) * N + i] = word;
            }
        }
    }
}

// ---------------------------------------------------------------------------
// Fused attention layer (R12-verified): STATIC double-buffering (rule-#20
// safe: named A/B buffers, two-step loop, all indices compile-time).
// P-gen: P' = max(E2[j], C1_i*S2[j]) (E1 cancels in softmax ratio, R11).
// Mask applied as bitwise AND on packed bf16 pairs (bit-exact, R7).
// L1: HEADS=4, D=64,  G=8, MW=2, grid (128,4), 512 thr, lb(512,2).
// L2: HEADS=1, D=128, G=8, MW=1, grid (256,1), 512 thr, lb(512,2).
// ---------------------------------------------------------------------------
template <int HEADS, int D, int DSL, int G, int MW, int OCC>
__global__ __launch_bounds__(G * 64, OCC) void attn_fused(
        const unsigned* __restrict__ maskT,             // [N/32][N]
        const __hip_bfloat16* __restrict__ WhB,          // [H][N/32][D/16][64][8]
        const float* __restrict__ C1g, const float* __restrict__ E2g,
        const float* __restrict__ S2g,
        float* __restrict__ outp) {
    constexpr int CTtot = D / 16;
    constexpr int CTT = CTtot / DSL;
    constexpr int CC = (D == 64) ? 1 : 2;
    constexpr int KSTEPS = N / (32 * G);
    static_assert(KSTEPS % 2 == 0, "two-step pipeline needs even KSTEPS");
    __shared__ float sh[MW * G * 16 * CC * 17];
    __shared__ float dsh[MW * G * 16];
    const int t = threadIdx.x;
    const int g = t >> 6, lane = t & 63;
    const int m = lane & 15, quad = lane >> 4;
    const int h = blockIdx.y / DSL, slc = blockIdx.y % DSL;
    const int i0 = blockIdx.x * (16 * MW);

    float c1v[MW];
#pragma unroll
    for (int mw = 0; mw < MW; mw++)
        c1v[mw] = C1g[(size_t)h * N + i0 + mw * 16 + m];

    // strength-reduced stream pointers
    const unsigned* mp = maskT + (size_t)(g * KSTEPS) * N + i0 + m;
    const float* ep = E2g + (size_t)h * N + g * (N / G) + quad * 8;
    const float* sp = S2g + (size_t)h * N + g * (N / G) + quad * 8;
    const bf16x8* bp = (const bf16x8*)WhB +
                       ((size_t)h * (N / 32) * CTtot +
                        (size_t)(g * KSTEPS) * CTtot + slc * CTT) * 64 + lane;

    const f32x4 zero = {0.f, 0.f, 0.f, 0.f};
    f32x4 acc[MW][CTT];
    f32x4 sac[MW];
#pragma unroll
    for (int mw = 0; mw < MW; mw++) {
        sac[mw] = zero;
#pragma unroll
        for (int ct = 0; ct < CTT; ct++) acc[mw][ct] = zero;
    }
    const short one_bf = (short)0x3F80;
    const bf16x8 ones = {one_bf, one_bf, one_bf, one_bf,
                         one_bf, one_bf, one_bf, one_bf};

    // ---- NAMED double-buffer state (no runtime indices anywhere) ----
    unsigned mwrdA[MW], mwrdB[MW];
    float4 e2loA, e2hiA, s2loA, s2hiA;
    float4 e2loB, e2hiB, s2loB, s2hiB;
    bf16x8 bfragA[CTT], bfragB[CTT];

    auto stage = [&](auto& mwrd_, float4& e2lo_, float4& e2hi_,
                     float4& s2lo_, float4& s2hi_, auto& bfrag_) {
#pragma unroll
        for (int mw = 0; mw < MW; mw++) mwrd_[mw] = mp[mw * 16];
        e2lo_ = *(const float4*)(ep);
        e2hi_ = *(const float4*)(ep + 4);
        s2lo_ = *(const float4*)(sp);
        s2hi_ = *(const float4*)(sp + 4);
#pragma unroll
        for (int ct = 0; ct < CTT; ct++) bfrag_[ct] = bp[ct * 64];
        mp += N; ep += 32; sp += 32; bp += CTtot * 64;
    };

    auto compute = [&](const auto& mwrd_, const float4& e2lo_,
                       const float4& e2hi_, const float4& s2lo_,
                       const float4& s2hi_, const auto& bfrag_) {
        const float Ee[8] = {e2lo_.x, e2lo_.y, e2lo_.z, e2lo_.w,
                             e2hi_.x, e2hi_.y, e2hi_.z, e2hi_.w};
        const float Se[8] = {s2lo_.x, s2lo_.y, s2lo_.z, s2lo_.w,
                             s2hi_.x, s2hi_.y, s2hi_.z, s2hi_.w};
        bf16x8 afr[MW];
#pragma unroll
        for (int mw = 0; mw < MW; mw++) {
            const unsigned mword = (mwrd_[mw] >> (quad * 8)) & 0xFFu;
            const unsigned spread = mword * 0x8001u;
            float p[8];
#pragma unroll
            for (int e = 0; e < 8; e++)
                p[e] = fmaxf(Ee[e], c1v[mw] * Se[e]);
            union { bf16x8 v; unsigned u32[4]; __hip_bfloat162 h2[4]; } u;
#pragma unroll
            for (int e2 = 0; e2 < 4; e2++) {
                u.h2[e2] = __float22bfloat162_rn(
                    make_float2(p[2 * e2], p[2 * e2 + 1]));
                const unsigned mk =
                    ((spread >> (2 * e2)) & 0x00010001u) * 0xFFFFu;
                u.u32[e2] &= mk;
            }
            afr[mw] = u.v;
        }
#pragma unroll
        for (int ct = 0; ct < CTT; ct++)
#pragma unroll
            for (int mw = 0; mw < MW; mw++)
                acc[mw][ct] = __builtin_amdgcn_mfma_f32_16x16x32_bf16(
                    afr[mw], bfrag_[ct], acc[mw][ct], 0, 0, 0);
#pragma unroll
        for (int mw = 0; mw < MW; mw++)
            sac[mw] = __builtin_amdgcn_mfma_f32_16x16x32_bf16(
                afr[mw], ones, sac[mw], 0, 0, 0);
    };

    stage(mwrdA, e2loA, e2hiA, s2loA, s2hiA, bfragA);
    for (int ks = 0; ks < KSTEPS; ks += 2) {
        stage(mwrdB, e2loB, e2hiB, s2loB, s2hiB, bfragB);   // prefetch odd
        compute(mwrdA, e2loA, e2hiA, s2loA, s2hiA, bfragA); // even step
        if (ks + 2 < KSTEPS)
            stage(mwrdA, e2loA, e2hiA, s2loA, s2hiA, bfragA); // prefetch even
        compute(mwrdB, e2loB, e2hiB, s2loB, s2hiB, bfragB); // odd step
    }

    // ---- epilogue: LDS cross-group reduction ----
#pragma unroll
    for (int rd = 0; rd < CTT / CC; rd++) {
#pragma unroll
        for (int mw = 0; mw < MW; mw++) {
#pragma unroll
            for (int cc = 0; cc < CC; cc++) {
#pragma unroll
                for (int r = 0; r < 4; r++)
                    sh[(((mw * G + g) * 16 + quad * 4 + r) * CC + cc) * 17 + m] =
                        acc[mw][rd * CC + cc][r];
            }
            if (rd == 0 && m == 0) {
#pragma unroll
                for (int r = 0; r < 4; r++)
                    dsh[(mw * G + g) * 16 + quad * 4 + r] = sac[mw][r];
            }
        }
        __syncthreads();
        if (t < 16 * CC * 16) {
            int row, chl;
            if (D == 64) { row = t & 15; chl = (t >> 4) & 15; }
            else         { chl = t & 31; row = (t >> 5) & 15; }
#pragma unroll
            for (int mw = 0; mw < MW; mw++) {
                float av = 0.f, ss = 0.f;
#pragma unroll
                for (int gg = 0; gg < G; gg++) {
                    av += sh[(((mw * G + gg) * 16 + row) * CC + (chl >> 4)) * 17 +
                             (chl & 15)];
                    ss += dsh[(mw * G + gg) * 16 + row];
                }
                float v = av / ss;
                v = (v > 0.f) ? v : (__builtin_amdgcn_exp2f(v * LOG2E) - 1.f);
                const int chg = h * D + slc * (CTT * 16) + rd * CC * 16 + chl;
                const int irow = i0 + mw * 16 + row;
                if (D == 64)
                    outp[(size_t)irow * (NHEADS * HID) + chg] = v;  // h1[i][ch]
                else
                    outp[(size_t)irow * D + chg] = v;               // out[i][ch]
            }
        }
        __syncthreads();
    }
}

// ---------------------------------------------------------------------------
// gemm2 via MFMA bf16-split: h1[4096][256] @ W2[256][128].
// Tail writes C1b / E2b / S2b for the E1-cancelled layer-2 P-gen.
// ---------------------------------------------------------------------------
__global__ __launch_bounds__(512, 2) void gemm2_kernel(
        const float* __restrict__ h1, const float* __restrict__ W2,
        const float* __restrict__ a2, __hip_bfloat16* __restrict__ WhB2,
        float* __restrict__ C1, float* __restrict__ E2, float* __restrict__ S2) {
    __shared__ float fred[8][16][2];
    const int t = threadIdx.x;
    const int w = t >> 6, lane = t & 63, m = lane & 15, quad = lane >> 4;
    const int i0 = blockIdx.x * 16;
    const float* arow = h1 + (size_t)(i0 + m) * IN_DIM;
    const float* wp = W2 + w * 16 + m;
    const f32x4 zero = {0.f, 0.f, 0.f, 0.f};
    f32x4 acc = zero;
    for (int ks = 0; ks < 8; ks++) {
        const int kb = ks * 32 + quad * 8;
        const float4 xa = *(const float4*)(arow + kb);
        const float4 xb = *(const float4*)(arow + kb + 4);
        const float xf[8] = {xa.x, xa.y, xa.z, xa.w, xb.x, xb.y, xb.z, xb.w};
        bf16x8 xh, xl, wh, wl;
#pragma unroll
        for (int e = 0; e < 8; e++) {
            const ushort2 s = bsplit(xf[e]);
            xh[e] = (short)s.x; xl[e] = (short)s.y;
        }
#pragma unroll
        for (int e = 0; e < 8; e++) {
            const ushort2 s = bsplit(wp[(size_t)(kb + e) * OUT_DIM]);
            wh[e] = (short)s.x; wl[e] = (short)s.y;
        }
        acc = __builtin_amdgcn_mfma_f32_16x16x32_bf16(xh, wh, acc, 0, 0, 0);
        acc = __builtin_amdgcn_mfma_f32_16x16x32_bf16(xl, wh, acc, 0, 0, 0);
        acc = __builtin_amdgcn_mfma_f32_16x16x32_bf16(xh, wl, acc, 0, 0, 0);
    }
    const int jblk = i0 >> 5, jb2 = (i0 >> 4) & 1;
#pragma unroll
    for (int r = 0; r < 4; r++) {
        const int jo = quad * 4 + r;
        const int lane_idx = m + 16 * (2 * jb2 + (jo >> 3));
        WhB2[(((size_t)jblk * 8 + w) * 64 + lane_idx) * 8 + (jo & 7)] =
            __float2bfloat16(acc[r]);
    }
    const float av1 = a2[w * 16 + m], av2 = a2[OUT_DIM + w * 16 + m];
    float s1[4], s2[4];
#pragma unroll
    for (int r = 0; r < 4; r++) { s1[r] = acc[r] * av1; s2[r] = acc[r] * av2; }
#pragma unroll
    for (int mm = 8; mm > 0; mm >>= 1) {
#pragma unroll
        for (int r = 0; r < 4; r++) {
            s1[r] += __shfl_xor(s1[r], mm, 64);
            s2[r] += __shfl_xor(s2[r], mm, 64);
        }
    }
    if (m == 0) {
#pragma unroll
        for (int r = 0; r < 4; r++) {
            fred[w][quad * 4 + r][0] = s1[r];
            fred[w][quad * 4 + r][1] = s2[r];
        }
    }
    __syncthreads();
    if (t < 32) {
        const int row = t & 15, fn = t >> 4;
        float s = 0.f;
#pragma unroll
        for (int w8 = 0; w8 < 8; w8++) s += fred[w8][row][fn];
        if (fn) {
            E2[i0 + row] = __builtin_amdgcn_exp2f(s * LOG2E);
            S2[i0 + row] = __builtin_amdgcn_exp2f(s * (0.5f * LOG2E));
        } else {
            C1[i0 + row] = __builtin_amdgcn_exp2f(s * (-0.5f * LOG2E));
        }
    }
}

// ---------------------------------------------------------------------------
extern "C" void kernel_launch(void* const* d_in, const int* in_sizes, int n_in,
                              void* d_out, int out_size, void* d_ws, size_t ws_size,
                              hipStream_t stream) {
    const float* x   = (const float*)d_in[0];
    const int*   adj = (const int*)d_in[1];
    const float* Wh_ = (const float*)d_in[2];
    const float* ah  = (const float*)d_in[3];
    const float* W2  = (const float*)d_in[4];
    const float* a2  = (const float*)d_in[5];
    float* out = (float*)d_out;

    float* ws = (float*)d_ws;
    float* C1a = ws;                                    // 4*N each
    float* E2a = C1a + (size_t)NHEADS * N;
    float* S2a = E2a + (size_t)NHEADS * N;
    float* C1b = S2a + (size_t)NHEADS * N;              // N each
    float* E2b = C1b + N;
    float* S2b = E2b + N;
    float* h1  = S2b + N;                               // N*256 fp32 (4MB)
    __hip_bfloat16* WhB1 = (__hip_bfloat16*)(h1 + (size_t)IN_DIM * N);  // 2MB
    __hip_bfloat16* WhB2 = WhB1 + (size_t)NHEADS * HID * N;            // 1MB
    unsigned* maskT = (unsigned*)(WhB2 + (size_t)OUT_DIM * N);         // 2MB

    prep_kernel<<<1280, 256, 0, stream>>>(x, Wh_, ah, adj, WhB1,
                                          C1a, E2a, S2a, maskT);
    attn_fused<NHEADS, HID, 1, 8, 2, 2>
        <<<dim3(N / 32, NHEADS), 512, 0, stream>>>(maskT, WhB1,
                                                   C1a, E2a, S2a, h1);
    gemm2_kernel<<<N / 16, 512, 0, stream>>>(h1, W2, a2, WhB2,
                                             C1b, E2b, S2b);
    attn_fused<1, OUT_DIM, 1, 8, 1, 2>
        <<<dim3(N / 16, 1), 512, 0, stream>>>(maskT, WhB2,
                                              C1b, E2b, S2b, out);
}